// Round 19
// baseline (122.565 us; speedup 1.0000x reference)
//
#include <hip/hip_runtime.h>
#include <hip/hip_bf16.h>
#include <math.h>

#define Gn 16
#define Nn 256
#define Kf 128
#define Hh 32
#define Dd 768
#define NEG_BIG (-3.0e38f)
#define PAD_XG  (1.0e10f)                    // pad-fold: ef = exp2(-huge) = +0
#define INV_A 0.3989422804014327f            // 1/2.5066256735058273
#define NHALF_LOG2E (-0.7213475204444817f)   // -0.5*log2(e)
#define HSIG_A 0.2837f                       // hard-sigmoid slope for 1.702v

typedef __attribute__((ext_vector_type(8))) short bf16x8;
typedef __attribute__((ext_vector_type(4))) float f32x4;

static __device__ __forceinline__ float fast_exp2(float x) {
#if __has_builtin(__builtin_amdgcn_exp2f)
    return __builtin_amdgcn_exp2f(x);
#else
    return exp2f(x);
#endif
}
static __device__ __forceinline__ float clamp01(float x) {
#if __has_builtin(__builtin_amdgcn_fmed3f)
    return __builtin_amdgcn_fmed3f(x, 0.f, 1.f);
#else
    return fminf(fmaxf(x, 0.f), 1.f);
#endif
}

static __device__ __forceinline__ unsigned short f2bf(float f) {
    union { float f; unsigned int u; } v; v.f = f;
    unsigned int r = v.u + 0x7FFF + ((v.u >> 16) & 1);   // RTNE
    return (unsigned short)(r >> 16);
}

// ---------------------------------------------------------------------------
// Prep: fragment-ordered bf16 weight tables + per-(g,k) gaussian coeffs.
// ---------------------------------------------------------------------------
__global__ __launch_bounds__(256)
void prep_kernel(const float* __restrict__ w1, const float* __restrict__ w2,
                 const int* __restrict__ tarr, const float* __restrict__ means,
                 const float* __restrict__ stds,
                 unsigned short* __restrict__ w1f, unsigned short* __restrict__ w2f,
                 float4* __restrict__ coef)
{
    const int idx = blockIdx.x * 256 + threadIdx.x;
    if (idx < 2048) {                    // w1 fragments: 2048 lanes x 8 elems
        const int lane = idx & 63;
        const int nf   = (idx >> 6) & 7;
        const int ks   = idx >> 9;
        const int l15 = lane & 15, lhi = lane >> 4;
        const int n = nf * 16 + l15;
        unsigned short v[8];
#pragma unroll
        for (int e = 0; e < 8; ++e) {
            const int k = ks * 32 + lhi * 8 + e;
            v[e] = f2bf(w1[k * Kf + n]);
        }
        *(uint4*)(w1f + (size_t)idx * 8) = *(const uint4*)v;
    } else if (idx < 2560) {             // w2 fragments: 512 lanes x 8
        const int f2 = idx - 2048;
        const int lane = f2 & 63;
        const int mf   = (f2 >> 6) & 1;
        const int ks   = f2 >> 7;
        const int l15 = lane & 15, lhi = lane >> 4;
        const int m = mf * 16 + l15;
        unsigned short v[8];
#pragma unroll
        for (int e = 0; e < 8; ++e) {
            const int k = ks * 32 + lhi * 8 + e;
            v[e] = f2bf(w2[k * Hh + m]);
        }
        *(uint4*)(w2f + (size_t)f2 * 8) = *(const uint4*)v;
    } else if (idx < 4608) {             // coef: (g, k)
        const int e3 = idx - 2560;
        const int g = e3 >> 7, k = e3 & 127;
        const int tg = tarr[g];
        const float mean = means[tg * Kf + k];
        const float sd   = fabsf(stds[tg * Kf + k]) + 1e-5f;
        const float inv  = 1.0f / sd;
        coef[g * Kf + k] =
            make_float4(mean, NHALF_LOG2E * inv * inv, log2f(inv * INV_A), 0.f);
    }
}

// ---------------------------------------------------------------------------
// Geom: dist/delta outputs + xg table (pad-folded) for all (g,i,j).
// Hoists the dependent atoms->pos->gather->xg chain OUT of the attn blocks.
// Block = (g, 4 i-rows); thread = j. 1024 blocks.
// ---------------------------------------------------------------------------
__global__ __launch_bounds__(256)
void geom_kernel(const float* __restrict__ pos,
                 const int* __restrict__ atoms,
                 const float* __restrict__ mul_w,
                 const float* __restrict__ bias_w,
                 float* __restrict__ xg_tab,
                 float* __restrict__ out_dist,
                 float* __restrict__ out_delta)
{
    const int j  = threadIdx.x;
    const int i0 = blockIdx.x * 4;
    const int g  = blockIdx.y;

    const int aj = atoms[g * Nn + j];
    float pjx = pos[(g * Nn + j) * 3 + 0];
    float pjy = pos[(g * Nn + j) * 3 + 1];
    float pjz = pos[(g * Nn + j) * 3 + 2];
    if (aj == 0) { pjx = 0.f; pjy = 0.f; pjz = 0.f; }

#pragma unroll
    for (int ii = 0; ii < 4; ++ii) {
        const int iv = i0 + ii;
        const int ai = atoms[g * Nn + iv];
        float pix = pos[(g * Nn + iv) * 3 + 0];
        float piy = pos[(g * Nn + iv) * 3 + 1];
        float piz = pos[(g * Nn + iv) * 3 + 2];
        if (ai == 0) { pix = 0.f; piy = 0.f; piz = 0.f; }
        const float dx = pjx - pix, dy = pjy - piy, dz = pjz - piz;
        const float sq = dx * dx + dy * dy + dz * dz;
        const float dist = (sq > 0.f) ? sqrtf(sq) : 0.f;
        const float inv_d = 1.f / (dist + 1e-5f);
        const size_t base = (size_t)(g * Nn + iv) * Nn + j;
        out_dist[base] = dist;
        out_delta[base * 3 + 0] = dx * inv_d;
        out_delta[base * 3 + 1] = dy * inv_d;
        out_delta[base * 3 + 2] = dz * inv_d;
        const int et = ai * 128 + aj;
        float xg = fmaf(mul_w[et], dist, bias_w[et]);
        if (aj == 0) xg = PAD_XG;          // ef -> +0 exactly
        xg_tab[base] = xg;
    }
}

// ---------------------------------------------------------------------------
// Attn: block per (g, i, j-half of 128). LDS = tile 32KB only; 4 blocks/CU.
// No phase-0: xg read via broadcast float4 loads from the L2-hot xg table.
// Barrier-free compute body (own-wave LDS program-ordered). Phase-1: lane =
// (k-quad, j-half): 4x b128 broadcast xg reads + 16x b64 packed ef writes.
// GEMM A-operands: coalesced 1KB wave bursts from fragment tables (L1-hot).
// Attn stores issue BEFORE the 2-barrier tail reduce (4MB ws, cheap merge).
// Tile swizzle: byte ^= ((row&7)<<4) within each 256B row.
// ---------------------------------------------------------------------------
__global__ __launch_bounds__(256, 4)
void graph3d_attn_kernel(const int* __restrict__ atoms,
                         const float* __restrict__ b1,
                         const float* __restrict__ b2,
                         const unsigned short* __restrict__ w1f,
                         const unsigned short* __restrict__ w2f,
                         const float4* __restrict__ coef,
                         const float* __restrict__ xg_tab,
                         float* __restrict__ ws_sum,
                         float* __restrict__ out_attn)
{
    const int tid  = threadIdx.x;
    const int half = blockIdx.x;       // j-half: 0 or 1
    const int i    = blockIdx.y;
    const int g    = blockIdx.z;
    const int j0   = half * 128;

    __shared__ __align__(16) unsigned short s_tile[128 * 128];  // ef then h

    const int lane = tid & 63, wq = tid >> 6;
    const int l15 = lane & 15, lhi = lane >> 4;

    // ---- phase 1: ef -> bf16 tile (own rows) + fp32 k-sums ----
    // lane = (k-quad kq, j-half jh): 4 b128 xg loads (global broadcast,
    // L2-hot), 16 b64 packed ef writes.
    const int kq = lane & 31;
    f32x4 ps = (f32x4){0.f, 0.f, 0.f, 0.f};
    {
        const int jh = lane >> 5;
        const float4 c0 = coef[g * Kf + 4 * kq + 0];
        const float4 c1 = coef[g * Kf + 4 * kq + 1];
        const float4 c2 = coef[g * Kf + 4 * kq + 2];
        const float4 c3 = coef[g * Kf + 4 * kq + 3];
        char* rowbase = (char*)s_tile + wq * 32 * 256;
        const float* xgp = xg_tab + (size_t)(g * Nn + i) * Nn + j0 + wq * 32
                           + jh * 16;
        const int colb = 8 * kq;           // bytes of k 4kq..4kq+3 (2B each)
#pragma unroll
        for (int q4 = 0; q4 < 4; ++q4) {
            const float4 x4 = *(const float4*)(xgp + q4 * 4);  // broadcast b128
#pragma unroll
            for (int u = 0; u < 4; ++u) {
                const int j = jh * 16 + q4 * 4 + u;            // local row
                const float x = ((const float*)&x4)[u];
                const float d0 = x - c0.x, d1 = x - c1.x;
                const float d2 = x - c2.x, d3 = x - c3.x;
                const float e0 = fast_exp2(fmaf(c0.y, d0 * d0, c0.z));
                const float e1 = fast_exp2(fmaf(c1.y, d1 * d1, c1.z));
                const float e2 = fast_exp2(fmaf(c2.y, d2 * d2, c2.z));
                const float e3 = fast_exp2(fmaf(c3.y, d3 * d3, c3.z));
                ps += (f32x4){e0, e1, e2, e3};
                const __hip_bfloat162 p0 = __float22bfloat162_rn(make_float2(e0, e1));
                const __hip_bfloat162 p1 = __float22bfloat162_rn(make_float2(e2, e3));
                uint2 u2;
                u2.x = *(const unsigned int*)&p0;
                u2.y = *(const unsigned int*)&p1;
                *(uint2*)(rowbase + j * 256 + (colb ^ ((j & 7) << 4))) = u2;
            }
        }
        // fold the two j-halves; lanes 0..31 hold the wave's k-sums
        ps.x += __shfl_xor(ps.x, 32);
        ps.y += __shfl_xor(ps.y, 32);
        ps.z += __shfl_xor(ps.z, 32);
        ps.w += __shfl_xor(ps.w, 32);
    }
    // no barrier: GEMM1 B-frags read only this wave's rows (program-ordered)

    // ---- GEMM1: D1[n][j] = w1^T x ef^T; A from coalesced fragment table ----
    const int jrow0 = wq * 32 + l15, jrow1 = jrow0 + 16;
    char* tb0 = (char*)s_tile + jrow0 * 256;
    char* tb1 = (char*)s_tile + jrow1 * 256;
    const int sw0 = (jrow0 & 7) << 4, sw1 = (jrow1 & 7) << 4;
    const unsigned short* w1p = w1f + lane * 8;        // + (ks*8+nf)*512
    const unsigned short* w2p = w2f + lane * 8;        // + (ks*2+mf)*512

    f32x4 acc[8][2];
#pragma unroll
    for (int a = 0; a < 8; ++a)
#pragma unroll
        for (int b = 0; b < 2; ++b) acc[a][b] = (f32x4){0.f, 0.f, 0.f, 0.f};

#pragma unroll
    for (int ks = 0; ks < 4; ++ks) {
        const int kb = ks * 64 + lhi * 16;
        const bf16x8 b0  = *(const bf16x8*)(tb0 + (kb ^ sw0));
        const bf16x8 b1f = *(const bf16x8*)(tb1 + (kb ^ sw1));
        bf16x8 a0[4];
#pragma unroll
        for (int nf = 0; nf < 4; ++nf)
            a0[nf] = *(const bf16x8*)(w1p + (ks * 8 + nf) * 512);
#pragma unroll
        for (int nf = 0; nf < 4; ++nf) {
            acc[nf][0] = __builtin_amdgcn_mfma_f32_16x16x32_bf16(a0[nf], b0,  acc[nf][0], 0, 0, 0);
            acc[nf][1] = __builtin_amdgcn_mfma_f32_16x16x32_bf16(a0[nf], b1f, acc[nf][1], 0, 0, 0);
        }
        bf16x8 a1[4];
#pragma unroll
        for (int nf = 0; nf < 4; ++nf)
            a1[nf] = *(const bf16x8*)(w1p + (ks * 8 + nf + 4) * 512);
#pragma unroll
        for (int nf = 0; nf < 4; ++nf) {
            acc[nf + 4][0] = __builtin_amdgcn_mfma_f32_16x16x32_bf16(a1[nf], b0,  acc[nf + 4][0], 0, 0, 0);
            acc[nf + 4][1] = __builtin_amdgcn_mfma_f32_16x16x32_bf16(a1[nf], b1f, acc[nf + 4][1], 0, 0, 0);
        }
    }

    // GELU epilogue: +b1 (L1-hit), hard-sigmoid (fmed3; attn threshold inf),
    // packed b64 writes to own rows
#pragma unroll
    for (int nf = 0; nf < 8; ++nf) {
        const float4 bbv = *(const float4*)(b1 + nf * 16 + lhi * 4);
        const f32x4 bb = (f32x4){bbv.x, bbv.y, bbv.z, bbv.w};
        const int colb = 32 * nf + 8 * lhi;
#pragma unroll
        for (int jf = 0; jf < 2; ++jf) {
            char* tb = jf ? tb1 : tb0;
            const int sw = jf ? sw1 : sw0;
            const f32x4 v = acc[nf][jf] + bb;
            f32x4 h;
#pragma unroll
            for (int r = 0; r < 4; ++r)
                h[r] = v[r] * clamp01(fmaf(HSIG_A, v[r], 0.5f));
            const __hip_bfloat162 p0 = __float22bfloat162_rn(make_float2(h.x, h.y));
            const __hip_bfloat162 p1 = __float22bfloat162_rn(make_float2(h.z, h.w));
            uint2 u;
            u.x = *(const unsigned int*)&p0;
            u.y = *(const unsigned int*)&p1;
            *(uint2*)(tb + (colb ^ sw)) = u;
        }
    }
    // no barrier: GEMM2 reads only this wave's rows

    // ---- GEMM2: D[m][j] = w2^T x h^T; A from coalesced fragment table ----
    f32x4 acc2[2][2];
#pragma unroll
    for (int a = 0; a < 2; ++a)
#pragma unroll
        for (int b = 0; b < 2; ++b) acc2[a][b] = (f32x4){0.f, 0.f, 0.f, 0.f};

#pragma unroll
    for (int ks = 0; ks < 4; ++ks) {
        const int kb = ks * 64 + lhi * 16;
        const bf16x8 bh0 = *(const bf16x8*)(tb0 + (kb ^ sw0));
        const bf16x8 bh1 = *(const bf16x8*)(tb1 + (kb ^ sw1));
#pragma unroll
        for (int mf = 0; mf < 2; ++mf) {
            const bf16x8 a2 = *(const bf16x8*)(w2p + (ks * 2 + mf) * 512);
            acc2[mf][0] = __builtin_amdgcn_mfma_f32_16x16x32_bf16(a2, bh0, acc2[mf][0], 0, 0, 0);
            acc2[mf][1] = __builtin_amdgcn_mfma_f32_16x16x32_bf16(a2, bh1, acc2[mf][1], 0, 0, 0);
        }
    }

    // attn stores first (overlap store latency with the tail reduce)
    const size_t attn_g = (size_t)g * Hh * (Nn * Nn) + (size_t)i * Nn + j0;
    const float4 b2lo = *(const float4*)(b2 + lhi * 4);
    const float4 b2hi = *(const float4*)(b2 + 16 + lhi * 4);
#pragma unroll
    for (int jf = 0; jf < 2; ++jf) {
        const int jloc = wq * 32 + jf * 16 + l15;
        const bool keep = atoms[g * Nn + j0 + jloc] != 0;
#pragma unroll
        for (int mf = 0; mf < 2; ++mf) {
            const float4 b2v = mf ? b2hi : b2lo;
            const f32x4 v = acc2[mf][jf] + (f32x4){b2v.x, b2v.y, b2v.z, b2v.w};
#pragma unroll
            for (int r = 0; r < 4; ++r) {
                const int m = mf * 16 + lhi * 4 + r;
                out_attn[attn_g + (size_t)m * (Nn * Nn) + jloc] =
                    keep ? v[r] : NEG_BIG;
            }
        }
    }

    // ---- tail: reduce the 4 waves' k-partials through the dead tile ----
    __syncthreads();                       // all waves done reading the tile
    if (lane < 32) {
        float* pt = (float*)s_tile;        // 2KB scratch: [wq][128]
        *(f32x4*)&pt[wq * 128 + 4 * kq] = ps;
    }
    __syncthreads();
    if (tid < 128) {
        const float* pt = (const float*)s_tile;
        const float s = (pt[tid] + pt[128 + tid]) + (pt[256 + tid] + pt[384 + tid]);
        ws_sum[((size_t)(g * Nn + i) * 2 + half) * Kf + tid] = s;
    }
}

// ---------------------------------------------------------------------------
// Merge: [4096 x 128] @ we[128 x 768] + be from ws half-partials (2 per row).
// Grid = 3 col-blocks x 256 row-groups (768 blocks).
// ---------------------------------------------------------------------------
__global__ __launch_bounds__(256)
void graph3d_merge_kernel(const float* __restrict__ ws_sum,
                          const float* __restrict__ we,
                          const float* __restrict__ be,
                          float* __restrict__ out_merge)
{
    const int tid = threadIdx.x;
    const int bd  = blockIdx.x;          // column block: 0..2
    const int r0  = blockIdx.y * 16;     // row group
    __shared__ __align__(16) float s_rows[16][128];

#pragma unroll
    for (int p = 0; p < 8; ++p) {
        const int e = p * 256 + tid;
        const int r = e >> 7, k = e & 127;
        const size_t gi = (size_t)(r0 + r);
        s_rows[r][k] = ws_sum[(gi * 2 + 0) * Kf + k] + ws_sum[(gi * 2 + 1) * Kf + k];
    }
    __syncthreads();

    const int col = bd * 256 + tid;
    float acc[16];
#pragma unroll
    for (int r = 0; r < 16; ++r) acc[r] = 0.f;

    for (int k4 = 0; k4 < 32; ++k4) {
        const int k = k4 * 4;
        const float w0  = we[(k + 0) * Dd + col];
        const float w1v = we[(k + 1) * Dd + col];
        const float w2v = we[(k + 2) * Dd + col];
        const float w3  = we[(k + 3) * Dd + col];
#pragma unroll
        for (int r = 0; r < 16; ++r) {
            const float4 s = ((const float4*)&s_rows[r][0])[k4];
            acc[r] = fmaf(s.x, w0, acc[r]);
            acc[r] = fmaf(s.y, w1v, acc[r]);
            acc[r] = fmaf(s.z, w2v, acc[r]);
            acc[r] = fmaf(s.w, w3, acc[r]);
        }
    }

    const float b = be[col];
#pragma unroll
    for (int r = 0; r < 16; ++r)
        out_merge[(size_t)(r0 + r) * Dd + col] = acc[r] + b;
}

// ---------------------------------------------------------------------------
extern "C" void kernel_launch(void* const* d_in, const int* in_sizes, int n_in,
                              void* d_out, int out_size, void* d_ws, size_t ws_size,
                              hipStream_t stream) {
    const float* pos    = (const float*)d_in[0];
    const int*   x      = (const int*)  d_in[1];
    const int*   t      = (const int*)  d_in[2];
    const float* means  = (const float*)d_in[3];
    const float* stds   = (const float*)d_in[4];
    const float* mul_w  = (const float*)d_in[5];
    const float* bias_w = (const float*)d_in[6];
    const float* w1     = (const float*)d_in[7];
    const float* b1     = (const float*)d_in[8];
    const float* w2     = (const float*)d_in[9];
    const float* b2     = (const float*)d_in[10];
    const float* we     = (const float*)d_in[11];
    const float* be     = (const float*)d_in[12];

    float* out = (float*)d_out;
    float* out_dist  = out;
    float* out_delta = out + (size_t)Gn * Nn * Nn;
    float* out_attn  = out + (size_t)Gn * Nn * Nn * 4;
    float* out_merge = out + (size_t)Gn * Nn * Nn * 4 + (size_t)Gn * Hh * Nn * Nn;

    // ws: 4MB ws_sum [g][i][half][k]; 4MB xg_tab [g][i][j]; w1f; w2f; coef
    float* ws_sum = (float*)d_ws;
    float* xg_tab = ws_sum + (size_t)Gn * Nn * 2 * Kf;
    unsigned short* w1f = (unsigned short*)(xg_tab + (size_t)Gn * Nn * Nn);
    unsigned short* w2f = w1f + 2048 * 8;
    float4* coef = (float4*)(w2f + 512 * 8);

    prep_kernel<<<18, 256, 0, stream>>>(w1, w2, t, means, stds, w1f, w2f, coef);

    dim3 gridG(Nn / 4, Gn);
    geom_kernel<<<gridG, 256, 0, stream>>>(pos, x, mul_w, bias_w,
                                           xg_tab, out_dist, out_delta);

    dim3 gridA(2, Nn, Gn);
    graph3d_attn_kernel<<<gridA, 256, 0, stream>>>(
        x, b1, b2, w1f, w2f, coef, xg_tab, ws_sum, out_attn);

    dim3 gridB(3, 256);
    graph3d_merge_kernel<<<gridB, 256, 0, stream>>>(
        ws_sum, we, be, out_merge);
}

// Round 20
// 112.528 us; speedup vs baseline: 1.0892x; 1.0892x over previous
//
#include <hip/hip_runtime.h>
#include <hip/hip_bf16.h>
#include <math.h>

#define Gn 16
#define Nn 256
#define Kf 128
#define Hh 32
#define Dd 768
#define NEG_BIG (-3.0e38f)
#define PAD_XG  (1.0e10f)                    // pad-fold: ef = exp2(-huge) = +0
#define INV_A 0.3989422804014327f            // 1/2.5066256735058273
#define NHALF_LOG2E (-0.7213475204444817f)   // -0.5*log2(e)
#define HSIG_A 0.2837f                       // hard-sigmoid slope for 1.702v

typedef __attribute__((ext_vector_type(8))) short bf16x8;
typedef __attribute__((ext_vector_type(4))) float f32x4;

static __device__ __forceinline__ float fast_exp2(float x) {
#if __has_builtin(__builtin_amdgcn_exp2f)
    return __builtin_amdgcn_exp2f(x);
#else
    return exp2f(x);
#endif
}
static __device__ __forceinline__ float clamp01(float x) {
#if __has_builtin(__builtin_amdgcn_fmed3f)
    return __builtin_amdgcn_fmed3f(x, 0.f, 1.f);
#else
    return fminf(fmaxf(x, 0.f), 1.f);
#endif
}

static __device__ __forceinline__ unsigned short f2bf(float f) {
    union { float f; unsigned int u; } v; v.f = f;
    unsigned int r = v.u + 0x7FFF + ((v.u >> 16) & 1);   // RTNE
    return (unsigned short)(r >> 16);
}

// ---------------------------------------------------------------------------
// Prep: fragment-ordered bf16 weight tables (one 16B chunk per lane, so a
// wave's A-operand load is a single coalesced 1KB burst):
//   w1f[(ks*8+nf)*64 + lane][e] = bf16(w1[k][n]), k=ks*32+(lane>>4)*8+e,
//                                 n=nf*16+(lane&15)          (32KB)
//   w2f[(ks*2+mf)*64 + lane][e] = bf16(w2[k][m]), m=mf*16+(lane&15)  (8KB)
// plus per-(g,k) gaussian coefficients {mean, Ak, Ck}.
// ---------------------------------------------------------------------------
__global__ __launch_bounds__(256)
void prep_kernel(const float* __restrict__ w1, const float* __restrict__ w2,
                 const int* __restrict__ tarr, const float* __restrict__ means,
                 const float* __restrict__ stds,
                 unsigned short* __restrict__ w1f, unsigned short* __restrict__ w2f,
                 float4* __restrict__ coef)
{
    const int idx = blockIdx.x * 256 + threadIdx.x;
    if (idx < 2048) {                    // w1 fragments: 2048 lanes x 8 elems
        const int lane = idx & 63;
        const int nf   = (idx >> 6) & 7;
        const int ks   = idx >> 9;
        const int l15 = lane & 15, lhi = lane >> 4;
        const int n = nf * 16 + l15;
        unsigned short v[8];
#pragma unroll
        for (int e = 0; e < 8; ++e) {
            const int k = ks * 32 + lhi * 8 + e;
            v[e] = f2bf(w1[k * Kf + n]);
        }
        *(uint4*)(w1f + (size_t)idx * 8) = *(const uint4*)v;
    } else if (idx < 2560) {             // w2 fragments: 512 lanes x 8
        const int f2 = idx - 2048;
        const int lane = f2 & 63;
        const int mf   = (f2 >> 6) & 1;
        const int ks   = f2 >> 7;
        const int l15 = lane & 15, lhi = lane >> 4;
        const int m = mf * 16 + l15;
        unsigned short v[8];
#pragma unroll
        for (int e = 0; e < 8; ++e) {
            const int k = ks * 32 + lhi * 8 + e;
            v[e] = f2bf(w2[k * Hh + m]);
        }
        *(uint4*)(w2f + (size_t)f2 * 8) = *(const uint4*)v;
    } else if (idx < 4608) {             // coef: (g, k)
        const int e3 = idx - 2560;
        const int g = e3 >> 7, k = e3 & 127;
        const int tg = tarr[g];
        const float mean = means[tg * Kf + k];
        const float sd   = fabsf(stds[tg * Kf + k]) + 1e-5f;
        const float inv  = 1.0f / sd;
        coef[g * Kf + k] =
            make_float4(mean, NHALF_LOG2E * inv * inv, log2f(inv * INV_A), 0.f);
    }
}

// ---------------------------------------------------------------------------
// Attn: block per (g, i, j-half of 128). LDS = tile 32KB only; 4 blocks/CU.
// Barrier-free compute body (waves independent; own-wave LDS program-ordered).
// Phase-0: lanes 0..31 compute the wave's own quadrant's 32 xg, park in own
// row 31. Phase-1: lane = (k-quad, j-half): 4x b128 broadcast xg reads + 16x
// b64 packed ef writes. GEMM A-operands: coalesced 1KB wave bursts from
// fragment tables (L1-hot). Attn stores issue BEFORE the 2-barrier tail
// reduce (dead-tile 4->1 partial reduce -> 4MB ws -> cheap merge).
// Tile swizzle: byte ^= ((row&7)<<4) within each 256B row.
// ---------------------------------------------------------------------------
__global__ __launch_bounds__(256, 4)
void graph3d_attn_kernel(const float* __restrict__ pos,
                         const int* __restrict__ atoms,
                         const float* __restrict__ mul_w,
                         const float* __restrict__ bias_w,
                         const float* __restrict__ b1,
                         const float* __restrict__ b2,
                         const unsigned short* __restrict__ w1f,
                         const unsigned short* __restrict__ w2f,
                         const float4* __restrict__ coef,
                         float* __restrict__ ws_sum,
                         float* __restrict__ out_dist,
                         float* __restrict__ out_delta,
                         float* __restrict__ out_attn)
{
    const int tid  = threadIdx.x;
    const int half = blockIdx.x;       // j-half: 0 or 1
    const int i    = blockIdx.y;
    const int g    = blockIdx.z;
    const int j0   = half * 128;

    __shared__ __align__(16) unsigned short s_tile[128 * 128];  // ef then h

    const int lane = tid & 63, wq = tid >> 6;
    const int l15 = lane & 15, lhi = lane >> 4;

    // ---- phase 0 (lanes 0..31): the wave's own quadrant's 32 j's ----
    if (lane < 32) {
        const int ai = atoms[g * Nn + i];
        float pix = pos[(g * Nn + i) * 3 + 0];
        float piy = pos[(g * Nn + i) * 3 + 1];
        float piz = pos[(g * Nn + i) * 3 + 2];
        if (ai == 0) { pix = 0.f; piy = 0.f; piz = 0.f; }

        const int j  = j0 + wq * 32 + lane;
        const int aj = atoms[g * Nn + j];
        float pjx = pos[(g * Nn + j) * 3 + 0];
        float pjy = pos[(g * Nn + j) * 3 + 1];
        float pjz = pos[(g * Nn + j) * 3 + 2];
        if (aj == 0) { pjx = 0.f; pjy = 0.f; pjz = 0.f; }
        const float dx = pjx - pix, dy = pjy - piy, dz = pjz - piz;
        const float sq = dx * dx + dy * dy + dz * dz;
        const float dist = (sq > 0.f) ? sqrtf(sq) : 0.f;
        const float inv_d = 1.f / (dist + 1e-5f);
        const size_t base = (size_t)(g * Nn + i) * Nn + j;
        out_dist[base] = dist;
        out_delta[base * 3 + 0] = dx * inv_d;
        out_delta[base * 3 + 1] = dy * inv_d;
        out_delta[base * 3 + 2] = dz * inv_d;
        const int et = ai * 128 + aj;
        float xg = fmaf(mul_w[et], dist, bias_w[et]);
        if (aj == 0) xg = PAD_XG;          // ef -> +0 exactly
        // park in the wave's OWN row 31 (program-ordered vs phase-1)
        ((float*)((char*)s_tile + (size_t)(wq * 32 + 31) * 256))[lane] = xg;
    }
    // no barrier: phase-1 reads only this wave's rows

    // ---- phase 1: ef -> bf16 tile (own rows) + fp32 k-sums ----
    // lane = (k-quad kq, j-half jh): 4 b128 xg reads, 16 b64 ef writes.
    const int kq = lane & 31;
    f32x4 ps = (f32x4){0.f, 0.f, 0.f, 0.f};
    {
        const int jh = lane >> 5;
        const float4 c0 = coef[g * Kf + 4 * kq + 0];
        const float4 c1 = coef[g * Kf + 4 * kq + 1];
        const float4 c2 = coef[g * Kf + 4 * kq + 2];
        const float4 c3 = coef[g * Kf + 4 * kq + 3];
        char* rowbase = (char*)s_tile + wq * 32 * 256;
        const float* xgp = (const float*)((char*)s_tile + (wq * 32 + 31) * 256)
                           + jh * 16;
        const int colb = 8 * kq;           // bytes of k 4kq..4kq+3 (2B each)
#pragma unroll
        for (int q4 = 0; q4 < 4; ++q4) {
            const float4 x4 = *(const float4*)(xgp + q4 * 4);  // broadcast b128
#pragma unroll
            for (int u = 0; u < 4; ++u) {
                const int j = jh * 16 + q4 * 4 + u;            // local row
                const float x = ((const float*)&x4)[u];
                const float d0 = x - c0.x, d1 = x - c1.x;
                const float d2 = x - c2.x, d3 = x - c3.x;
                const float e0 = fast_exp2(fmaf(c0.y, d0 * d0, c0.z));
                const float e1 = fast_exp2(fmaf(c1.y, d1 * d1, c1.z));
                const float e2 = fast_exp2(fmaf(c2.y, d2 * d2, c2.z));
                const float e3 = fast_exp2(fmaf(c3.y, d3 * d3, c3.z));
                ps += (f32x4){e0, e1, e2, e3};
                const __hip_bfloat162 p0 = __float22bfloat162_rn(make_float2(e0, e1));
                const __hip_bfloat162 p1 = __float22bfloat162_rn(make_float2(e2, e3));
                uint2 u2;
                u2.x = *(const unsigned int*)&p0;
                u2.y = *(const unsigned int*)&p1;
                *(uint2*)(rowbase + j * 256 + (colb ^ ((j & 7) << 4))) = u2;
            }
        }
        // fold the two j-halves; lanes 0..31 hold the wave's k-sums
        ps.x += __shfl_xor(ps.x, 32);
        ps.y += __shfl_xor(ps.y, 32);
        ps.z += __shfl_xor(ps.z, 32);
        ps.w += __shfl_xor(ps.w, 32);
    }
    // no barrier: GEMM1 B-frags read only this wave's rows (program-ordered)

    // ---- GEMM1: D1[n][j] = w1^T x ef^T; A from coalesced fragment table ----
    const int jrow0 = wq * 32 + l15, jrow1 = jrow0 + 16;
    char* tb0 = (char*)s_tile + jrow0 * 256;
    char* tb1 = (char*)s_tile + jrow1 * 256;
    const int sw0 = (jrow0 & 7) << 4, sw1 = (jrow1 & 7) << 4;
    const unsigned short* w1p = w1f + lane * 8;        // + (ks*8+nf)*512
    const unsigned short* w2p = w2f + lane * 8;        // + (ks*2+mf)*512

    f32x4 acc[8][2];
#pragma unroll
    for (int a = 0; a < 8; ++a)
#pragma unroll
        for (int b = 0; b < 2; ++b) acc[a][b] = (f32x4){0.f, 0.f, 0.f, 0.f};

#pragma unroll
    for (int ks = 0; ks < 4; ++ks) {
        const int kb = ks * 64 + lhi * 16;
        const bf16x8 b0  = *(const bf16x8*)(tb0 + (kb ^ sw0));
        const bf16x8 b1f = *(const bf16x8*)(tb1 + (kb ^ sw1));
        bf16x8 a0[4];
#pragma unroll
        for (int nf = 0; nf < 4; ++nf)
            a0[nf] = *(const bf16x8*)(w1p + (ks * 8 + nf) * 512);
#pragma unroll
        for (int nf = 0; nf < 4; ++nf) {
            acc[nf][0] = __builtin_amdgcn_mfma_f32_16x16x32_bf16(a0[nf], b0,  acc[nf][0], 0, 0, 0);
            acc[nf][1] = __builtin_amdgcn_mfma_f32_16x16x32_bf16(a0[nf], b1f, acc[nf][1], 0, 0, 0);
        }
        bf16x8 a1[4];
#pragma unroll
        for (int nf = 0; nf < 4; ++nf)
            a1[nf] = *(const bf16x8*)(w1p + (ks * 8 + nf + 4) * 512);
#pragma unroll
        for (int nf = 0; nf < 4; ++nf) {
            acc[nf + 4][0] = __builtin_amdgcn_mfma_f32_16x16x32_bf16(a1[nf], b0,  acc[nf + 4][0], 0, 0, 0);
            acc[nf + 4][1] = __builtin_amdgcn_mfma_f32_16x16x32_bf16(a1[nf], b1f, acc[nf + 4][1], 0, 0, 0);
        }
    }

    // GELU epilogue: +b1 (L1-hit), hard-sigmoid (fmed3; attn threshold inf),
    // packed b64 writes to own rows
#pragma unroll
    for (int nf = 0; nf < 8; ++nf) {
        const float4 bbv = *(const float4*)(b1 + nf * 16 + lhi * 4);
        const f32x4 bb = (f32x4){bbv.x, bbv.y, bbv.z, bbv.w};
        const int colb = 32 * nf + 8 * lhi;
#pragma unroll
        for (int jf = 0; jf < 2; ++jf) {
            char* tb = jf ? tb1 : tb0;
            const int sw = jf ? sw1 : sw0;
            const f32x4 v = acc[nf][jf] + bb;
            f32x4 h;
#pragma unroll
            for (int r = 0; r < 4; ++r)
                h[r] = v[r] * clamp01(fmaf(HSIG_A, v[r], 0.5f));
            const __hip_bfloat162 p0 = __float22bfloat162_rn(make_float2(h.x, h.y));
            const __hip_bfloat162 p1 = __float22bfloat162_rn(make_float2(h.z, h.w));
            uint2 u;
            u.x = *(const unsigned int*)&p0;
            u.y = *(const unsigned int*)&p1;
            *(uint2*)(tb + (colb ^ sw)) = u;
        }
    }
    // no barrier: GEMM2 reads only this wave's rows

    // ---- GEMM2: D[m][j] = w2^T x h^T; A from coalesced fragment table ----
    f32x4 acc2[2][2];
#pragma unroll
    for (int a = 0; a < 2; ++a)
#pragma unroll
        for (int b = 0; b < 2; ++b) acc2[a][b] = (f32x4){0.f, 0.f, 0.f, 0.f};

#pragma unroll
    for (int ks = 0; ks < 4; ++ks) {
        const int kb = ks * 64 + lhi * 16;
        const bf16x8 bh0 = *(const bf16x8*)(tb0 + (kb ^ sw0));
        const bf16x8 bh1 = *(const bf16x8*)(tb1 + (kb ^ sw1));
#pragma unroll
        for (int mf = 0; mf < 2; ++mf) {
            const bf16x8 a2 = *(const bf16x8*)(w2p + (ks * 2 + mf) * 512);
            acc2[mf][0] = __builtin_amdgcn_mfma_f32_16x16x32_bf16(a2, bh0, acc2[mf][0], 0, 0, 0);
            acc2[mf][1] = __builtin_amdgcn_mfma_f32_16x16x32_bf16(a2, bh1, acc2[mf][1], 0, 0, 0);
        }
    }

    // attn stores first (overlap store latency with the tail reduce)
    const size_t attn_g = (size_t)g * Hh * (Nn * Nn) + (size_t)i * Nn + j0;
    const float4 b2lo = *(const float4*)(b2 + lhi * 4);
    const float4 b2hi = *(const float4*)(b2 + 16 + lhi * 4);
#pragma unroll
    for (int jf = 0; jf < 2; ++jf) {
        const int jloc = wq * 32 + jf * 16 + l15;
        const bool keep = atoms[g * Nn + j0 + jloc] != 0;
#pragma unroll
        for (int mf = 0; mf < 2; ++mf) {
            const float4 b2v = mf ? b2hi : b2lo;
            const f32x4 v = acc2[mf][jf] + (f32x4){b2v.x, b2v.y, b2v.z, b2v.w};
#pragma unroll
            for (int r = 0; r < 4; ++r) {
                const int m = mf * 16 + lhi * 4 + r;
                out_attn[attn_g + (size_t)m * (Nn * Nn) + jloc] =
                    keep ? v[r] : NEG_BIG;
            }
        }
    }

    // ---- tail: reduce the 4 waves' k-partials through the dead tile ----
    __syncthreads();                       // all waves done reading the tile
    if (lane < 32) {
        float* pt = (float*)s_tile;        // 2KB scratch: [wq][128]
        *(f32x4*)&pt[wq * 128 + 4 * kq] = ps;
    }
    __syncthreads();
    if (tid < 128) {
        const float* pt = (const float*)s_tile;
        const float s = (pt[tid] + pt[128 + tid]) + (pt[256 + tid] + pt[384 + tid]);
        ws_sum[((size_t)(g * Nn + i) * 2 + half) * Kf + tid] = s;
    }
}

// ---------------------------------------------------------------------------
// Merge: [4096 x 128] @ we[128 x 768] + be from ws half-partials (2 per row).
// Grid = 3 col-blocks x 256 row-groups (768 blocks).
// ---------------------------------------------------------------------------
__global__ __launch_bounds__(256)
void graph3d_merge_kernel(const float* __restrict__ ws_sum,
                          const float* __restrict__ we,
                          const float* __restrict__ be,
                          float* __restrict__ out_merge)
{
    const int tid = threadIdx.x;
    const int bd  = blockIdx.x;          // column block: 0..2
    const int r0  = blockIdx.y * 16;     // row group
    __shared__ __align__(16) float s_rows[16][128];

#pragma unroll
    for (int p = 0; p < 8; ++p) {
        const int e = p * 256 + tid;
        const int r = e >> 7, k = e & 127;
        const size_t gi = (size_t)(r0 + r);
        s_rows[r][k] = ws_sum[(gi * 2 + 0) * Kf + k] + ws_sum[(gi * 2 + 1) * Kf + k];
    }
    __syncthreads();

    const int col = bd * 256 + tid;
    float acc[16];
#pragma unroll
    for (int r = 0; r < 16; ++r) acc[r] = 0.f;

    for (int k4 = 0; k4 < 32; ++k4) {
        const int k = k4 * 4;
        const float w0  = we[(k + 0) * Dd + col];
        const float w1v = we[(k + 1) * Dd + col];
        const float w2v = we[(k + 2) * Dd + col];
        const float w3  = we[(k + 3) * Dd + col];
#pragma unroll
        for (int r = 0; r < 16; ++r) {
            const float4 s = ((const float4*)&s_rows[r][0])[k4];
            acc[r] = fmaf(s.x, w0, acc[r]);
            acc[r] = fmaf(s.y, w1v, acc[r]);
            acc[r] = fmaf(s.z, w2v, acc[r]);
            acc[r] = fmaf(s.w, w3, acc[r]);
        }
    }

    const float b = be[col];
#pragma unroll
    for (int r = 0; r < 16; ++r)
        out_merge[(size_t)(r0 + r) * Dd + col] = acc[r] + b;
}

// ---------------------------------------------------------------------------
extern "C" void kernel_launch(void* const* d_in, const int* in_sizes, int n_in,
                              void* d_out, int out_size, void* d_ws, size_t ws_size,
                              hipStream_t stream) {
    const float* pos    = (const float*)d_in[0];
    const int*   x      = (const int*)  d_in[1];
    const int*   t      = (const int*)  d_in[2];
    const float* means  = (const float*)d_in[3];
    const float* stds   = (const float*)d_in[4];
    const float* mul_w  = (const float*)d_in[5];
    const float* bias_w = (const float*)d_in[6];
    const float* w1     = (const float*)d_in[7];
    const float* b1     = (const float*)d_in[8];
    const float* w2     = (const float*)d_in[9];
    const float* b2     = (const float*)d_in[10];
    const float* we     = (const float*)d_in[11];
    const float* be     = (const float*)d_in[12];

    float* out = (float*)d_out;
    float* out_dist  = out;
    float* out_delta = out + (size_t)Gn * Nn * Nn;
    float* out_attn  = out + (size_t)Gn * Nn * Nn * 4;
    float* out_merge = out + (size_t)Gn * Nn * Nn * 4 + (size_t)Gn * Hh * Nn * Nn;

    // ws: 4MB fp32 ws_sum [g][i][half][k]; w1f 32KB; w2f 8KB; coef 32KB
    float* ws_sum = (float*)d_ws;
    unsigned short* w1f = (unsigned short*)((char*)d_ws + (size_t)Gn * Nn * 2 * Kf * 4);
    unsigned short* w2f = w1f + 2048 * 8;
    float4* coef = (float4*)(w2f + 512 * 8);

    prep_kernel<<<18, 256, 0, stream>>>(w1, w2, t, means, stds, w1f, w2f, coef);

    dim3 gridA(2, Nn, Gn);
    graph3d_attn_kernel<<<gridA, 256, 0, stream>>>(
        pos, x, mul_w, bias_w, b1, b2, w1f, w2f, coef,
        ws_sum, out_dist, out_delta, out_attn);

    dim3 gridB(3, 256);
    graph3d_merge_kernel<<<gridB, 256, 0, stream>>>(
        ws_sum, we, be, out_merge);
}